// Round 6
// baseline (1296.323 us; speedup 1.0000x reference)
//
#include <hip/hip_runtime.h>
#include <hip/hip_fp16.h>
#include <stdint.h>

typedef _Float16 f16;
typedef _Float16 f16x8 __attribute__((ext_vector_type(8)));
typedef float f32x4 __attribute__((ext_vector_type(4)));

#define NB 32768      // batch
#define LAYERS 6
#define AKP 192       // HALF + COND padded 160 -> 192 (3 chunks of 64)
#define HID 1024

// async global->LDS, 16B per lane. LDS dest is wave-uniform base + lane*16.
__device__ __forceinline__ void async_copy16(const void* g, void* l) {
  __builtin_amdgcn_global_load_lds(
      (const __attribute__((address_space(1))) void*)g,
      (__attribute__((address_space(3))) void*)l, 16, 0, 0);
}

// ---------------------------------------------------------------------------
// prep: z = T (fp32 working state lives in d_out), log_det = 0,
// A[:, :32] = f16(T[:, 32:]) (layer0 unmasked), A[:, 32:160] = f16(cond),
// A[:, 160:192] = 0 (K padding; ws is poisoned each call, must re-zero)
// ---------------------------------------------------------------------------
__global__ void prep_batch(const float* __restrict__ T, const float* __restrict__ cond,
                           float* __restrict__ z, float* __restrict__ ld,
                           f16* __restrict__ A)
{
  const int S1 = NB * 64;
  const int S2 = S1 + NB;
  const int S3 = S2 + NB * 32;
  const int S4 = S3 + NB * 128;
  const int S5 = S4 + NB * 32;
  for (int i = blockIdx.x * blockDim.x + threadIdx.x; i < S5;
       i += gridDim.x * blockDim.x) {
    if (i < S1) {
      z[i] = T[i];
    } else if (i < S2) {
      ld[i - S1] = 0.0f;
    } else if (i < S3) {
      int r = i - S2;
      int row = r >> 5, j = r & 31;
      A[(size_t)row * AKP + j] = (f16)T[row * 64 + 32 + j];
    } else if (i < S4) {
      int r = i - S3;
      int row = r >> 7, j = r & 127;
      A[(size_t)row * AKP + 32 + j] = (f16)cond[r];
    } else {
      int r = i - S4;
      int row = r >> 5, j = r & 31;
      A[(size_t)row * AKP + 160 + j] = (f16)0.0f;
    }
  }
}

// Convert weights fp32 -> f16, transposed per layer to (N x K) row-major.
// W1t is K-padded to 192 with zeros.
__global__ void prep_weights(const float* __restrict__ W1, const float* __restrict__ W2,
                             const float* __restrict__ W3,
                             f16* __restrict__ W1t, f16* __restrict__ W2t,
                             f16* __restrict__ W3t)
{
  const int N2 = 6 << 20;               // W2t elems: 6*1024*1024
  const int N1 = N2 + 6 * 1024 * AKP;   // + W1t (padded)
  const int N3 = N1 + 6 * 64 * 1024;    // + W3t
  for (int i = blockIdx.x * blockDim.x + threadIdx.x; i < N3;
       i += gridDim.x * blockDim.x) {
    if (i < N2) {
      int l = i >> 20, r = i & 0xFFFFF, n = r >> 10, k = r & 1023;
      W2t[i] = (f16)W2[((size_t)l << 20) + ((size_t)k << 10) + n];
    } else if (i < N1) {
      int t = i - N2;
      int l = t / (1024 * AKP), r = t % (1024 * AKP), n = r / AKP, k = r % AKP;
      W1t[t] = (k < 160) ? (f16)W1[(size_t)l * 163840 + (size_t)k * 1024 + n]
                         : (f16)0.0f;
    } else {
      int t = i - N1;
      int l = t >> 16, r = t & 0xFFFF, n = r >> 10, k = r & 1023;
      W3t[t] = (f16)W3[((size_t)l << 16) + ((size_t)k << 6) + n];
    }
  }
}

// ---------------------------------------------------------------------------
// GEMM (relu): C[M x 1024] = relu(A[M x K] @ Wt^T + bias), C in f16.
// Restructured K-loop (R6): 128x128 block, 4 waves, wave-tile 64x64.
//  - A: direct global->VGPR fragments (never LDS). 16 rows x 64 B per load,
//    L1-served for the duplicated wave pair. Halves LDS traffic.
//  - B: LDS double-buffered in K=64 chunks (2 x 16 KB), staged with
//    global_load_lds, XOR swizzle chunk^(row&7) -> <=2-way on reads.
//  - ONE barrier per chunk (2 k-steps): barrier -> stage B(c+1) -> compute.
//    vmcnt(0) drain lands a full chunk-compute (~2000 cyc) after issue.
//  - 3 blocks/CU (acc 64 AGPR, LDS 32 KB).
// Per-CU sub-step: MFMA ~931 cyc vs LDS ~770 -> matrix-pipe-bound.
// ---------------------------------------------------------------------------
__global__ __launch_bounds__(256, 3)
void gemm12(const f16* __restrict__ A, const int K,   // K in {192, 1024}
            const f16* __restrict__ Wt,               // 1024 x K (pre-transposed)
            const float* __restrict__ bias,
            f16* __restrict__ C)
{
  __shared__ __align__(16) f16 Bs[2][128 * 64];       // 16 KB per buffer
  const int tid  = threadIdx.x;
  const int wave = tid >> 6;
  const int lane = tid & 63;
  const int c15  = lane & 15;
  const int quad = lane >> 4;
  const int wm = (wave & 1) * 64;
  const int wn = (wave >> 1) * 64;

  // XCD swizzle: grid 2048 = 8 XCDs x 32 row-groups x 8 col-blocks, col fastest
  const int b = blockIdx.x;
  const int x = b & 7, i = b >> 3;
  const long rowStart = (long)(x * 32 + (i >> 3)) * 128;
  const long colStart = (long)(i & 7) * 128;

  const f16* Bb = Wt + colStart * K;
  const f16* Arow[4];
#pragma unroll
  for (int mi = 0; mi < 4; ++mi)
    Arow[mi] = A + (rowStart + wm + mi * 16 + c15) * (long)K + quad * 8;

  // B staging: physical slot p = q*256+tid; row = q*32+(tid>>3), physChunk =
  // tid&7; fetch logical chunk physChunk^(row&7) -> reads are bank-spread.
  const int brow = tid >> 3;
  const int bkc  = ((tid & 7) ^ (brow & 7)) * 8;

  auto stageB = [&](int c, int sel) {
    const long kb = (long)c * 64;
    f16* bs = &Bs[sel][0];
#pragma unroll
    for (int q = 0; q < 4; ++q)
      async_copy16(Bb + (long)(q * 32 + brow) * K + kb + bkc,
                   bs + (q * 256 + wave * 64) * 8);
  };

  f32x4 acc[4][4] = {};
  const int nC = K >> 6;

  stageB(0, 0);
  for (int c = 0; c < nC; ++c) {
    __syncthreads();                 // drains stageB(c), issued one chunk ago
    if (c + 1 < nC) stageB(c + 1, (c + 1) & 1);
    const f16* bs = &Bs[c & 1][0];
    const long kb = (long)c * 64;

#pragma unroll
    for (int s = 0; s < 2; ++s) {
      f16x8 a[4], bf[4];
#pragma unroll
      for (int mi = 0; mi < 4; ++mi)
        a[mi] = *(const f16x8*)(Arow[mi] + kb + s * 32);
#pragma unroll
      for (int ni = 0; ni < 4; ++ni) {
        const int R = wn + ni * 16 + c15;
        const int phys = (s * 4 + quad) ^ (R & 7);
        bf[ni] = *(const f16x8*)&bs[(R * 8 + phys) * 8];
      }
#pragma unroll
      for (int mi = 0; mi < 4; ++mi)
#pragma unroll
        for (int ni = 0; ni < 4; ++ni)
          acc[mi][ni] = __builtin_amdgcn_mfma_f32_16x16x32_f16(
              a[mi], bf[ni], acc[mi][ni], 0, 0, 0);
    }
  }

  // epilogue: bias + relu + f16 store. C/D layout: col=lane&15, row=quad*4+r
#pragma unroll
  for (int ni = 0; ni < 4; ++ni) {
    const long gn = colStart + wn + ni * 16 + c15;
    const float bv = bias[gn];
#pragma unroll
    for (int mi = 0; mi < 4; ++mi) {
#pragma unroll
      for (int r = 0; r < 4; ++r) {
        const long gm = rowStart + wm + mi * 16 + quad * 4 + r;
        float v = acc[mi][ni][r] + bv;
        v = fmaxf(v, 0.0f);
        C[gm * HID + gn] = (f16)v;
      }
    }
  }
}

// ---------------------------------------------------------------------------
// GEMM3 (N=64) + coupling epilogue. BM=64, 4 waves, wave-tile 16x64.
// Same R6 structure: A direct global->VGPR, B (W3t) in K=64-chunk LDS dbuf
// (2 x 8 KB), one barrier per chunk. grid 512 -> 2 blocks/CU.
// s-col j and t-col j+32 share lane & reg slot -> no shuffles.
// Writes y to z (fp32, in d_out) and to Anext[:, :32] (f16, next layer input).
// ---------------------------------------------------------------------------
__global__ __launch_bounds__(256, 4)
void gemm3_coupling(const f16* __restrict__ X2, const f16* __restrict__ W3t,
                    const float* __restrict__ b3, float* __restrict__ z,
                    float* __restrict__ log_det, f16* __restrict__ Anext,
                    const int maskoff)
{
  __shared__ __align__(16) f16 Bs[2][64 * 64];        // 8 KB per buffer
  const int tid = threadIdx.x;
  const int wave = tid >> 6, lane = tid & 63;
  const int c15 = lane & 15, quad = lane >> 4;
  const long rowStart = (long)blockIdx.x * 64;

  const f16* Arow = X2 + (rowStart + wave * 16 + c15) * (long)HID + quad * 8;

  const int brow = tid >> 3;            // 0..31 (+q*32)
  const int bkc  = ((tid & 7) ^ (brow & 7)) * 8;

  auto stageB = [&](int c, int sel) {
    const long kb = (long)c * 64;
    f16* bs = &Bs[sel][0];
#pragma unroll
    for (int q = 0; q < 2; ++q)
      async_copy16(W3t + (long)(q * 32 + brow) * HID + kb + bkc,
                   bs + (q * 256 + wave * 64) * 8);
  };

  f32x4 acc[4] = {};

  stageB(0, 0);
  for (int c = 0; c < 16; ++c) {
    __syncthreads();
    if (c + 1 < 16) stageB(c + 1, (c + 1) & 1);
    const f16* bs = &Bs[c & 1][0];
    const long kb = (long)c * 64;

#pragma unroll
    for (int s = 0; s < 2; ++s) {
      f16x8 a = *(const f16x8*)(Arow + kb + s * 32);
      f16x8 bf[4];
#pragma unroll
      for (int ni = 0; ni < 4; ++ni) {
        const int R = ni * 16 + c15;
        const int phys = (s * 4 + quad) ^ (R & 7);
        bf[ni] = *(const f16x8*)&bs[(R * 8 + phys) * 8];
      }
#pragma unroll
      for (int ni = 0; ni < 4; ++ni)
        acc[ni] = __builtin_amdgcn_mfma_f32_16x16x32_f16(a, bf[ni], acc[ni], 0, 0, 0);
    }
  }

  float sp[4] = {0.0f, 0.0f, 0.0f, 0.0f};
#pragma unroll
  for (int ni = 0; ni < 2; ++ni) {
    const int j = ni * 16 + c15;          // s-column 0..31
    const float bs = b3[j];
    const float bt = b3[32 + j];
#pragma unroll
    for (int r = 0; r < 4; ++r) {
      const long gm = rowStart + wave * 16 + quad * 4 + r;
      const float sv = acc[ni][r] + bs;
      const float e2 = __expf(2.0f * sv);            // tanh via exp
      const float s  = 1.0f - 2.0f / (e2 + 1.0f);
      const float tv = acc[ni + 2][r] + bt;
      const float m  = z[gm * 64 + maskoff + j];
      const float y  = fmaf(m, __expf(s), tv);
      z[gm * 64 + maskoff + j] = y;
      Anext[gm * AKP + j] = (f16)y;   // next layer's unmasked input
      sp[r] += s;
    }
  }
#pragma unroll
  for (int r = 0; r < 4; ++r) {
    float v = sp[r];
    v += __shfl_xor(v, 1);
    v += __shfl_xor(v, 2);
    v += __shfl_xor(v, 4);
    v += __shfl_xor(v, 8);
    if (c15 == 0) {
      const long gm = rowStart + wave * 16 + quad * 4 + r;
      log_det[gm] += v;   // only this thread touches this row this layer
    }
  }
}

// ---------------------------------------------------------------------------
extern "C" void kernel_launch(void* const* d_in, const int* in_sizes, int n_in,
                              void* d_out, int out_size, void* d_ws, size_t ws_size,
                              hipStream_t stream) {
  (void)in_sizes; (void)n_in; (void)out_size; (void)ws_size;
  const float* T    = (const float*)d_in[0];
  const float* cond = (const float*)d_in[1];
  const float* W1   = (const float*)d_in[2];
  const float* b1   = (const float*)d_in[3];
  const float* W2   = (const float*)d_in[4];
  const float* b2   = (const float*)d_in[5];
  const float* W3   = (const float*)d_in[6];
  const float* b3   = (const float*)d_in[7];

  float* z  = (float*)d_out;                 // B x 64 working state = output
  float* ld = z + (size_t)NB * 64;           // B log_det

  f16* A   = (f16*)d_ws;                     // B x 192 (padded)
  f16* X1  = A   + (size_t)NB * AKP;         // B x 1024
  f16* X2  = X1  + (size_t)NB * HID;         // B x 1024
  f16* W1t = X2  + (size_t)NB * HID;         // 6 x 1024 x 192 (padded)
  f16* W2t = W1t + (size_t)6 * 1024 * AKP;   // 6 x 1024 x 1024
  f16* W3t = W2t + ((size_t)6 << 20);        // 6 x 64 x 1024

  prep_batch<<<2048, 256, 0, stream>>>(T, cond, z, ld, A);
  prep_weights<<<2048, 256, 0, stream>>>(W1, W2, W3, W1t, W2t, W3t);

  const int g12 = (NB / 128) * (HID / 128);  // 2048 blocks
  for (int l = 0; l < LAYERS; ++l) {
    gemm12<<<g12, 256, 0, stream>>>(A, AKP, W1t + (size_t)l * 1024 * AKP,
                                    b1 + l * 1024, X1);
    gemm12<<<g12, 256, 0, stream>>>(X1, HID, W2t + ((size_t)l << 20),
                                    b2 + l * 1024, X2);
    const int maskoff = (l & 1) ? 32 : 0;
    gemm3_coupling<<<NB / 64, 256, 0, stream>>>(X2, W3t + (size_t)l * 64 * 1024,
                                                b3 + l * 64, z, ld, A, maskoff);
  }
}

// Round 7
// 899.748 us; speedup vs baseline: 1.4408x; 1.4408x over previous
//
#include <hip/hip_runtime.h>
#include <hip/hip_fp16.h>
#include <stdint.h>

typedef _Float16 f16;
typedef _Float16 f16x8 __attribute__((ext_vector_type(8)));
typedef float f32x4 __attribute__((ext_vector_type(4)));

#define NB 32768      // batch
#define LAYERS 6
#define AK 160        // HALF + COND
#define HID 1024

// async global->LDS, 16B per lane. LDS dest is wave-uniform base + lane*16.
__device__ __forceinline__ void async_copy16(const void* g, void* l) {
  __builtin_amdgcn_global_load_lds(
      (const __attribute__((address_space(1))) void*)g,
      (__attribute__((address_space(3))) void*)l, 16, 0, 0);
}

// ---------------------------------------------------------------------------
// prep: z = T (fp32 working state lives in d_out), log_det = 0,
// A[:, :32] = f16(T[:, 32:]) (layer0 unmasked), A[:, 32:160] = f16(cond)
// ---------------------------------------------------------------------------
__global__ void prep_batch(const float* __restrict__ T, const float* __restrict__ cond,
                           float* __restrict__ z, float* __restrict__ ld,
                           f16* __restrict__ A)
{
  const int S1 = NB * 64;
  const int S2 = S1 + NB;
  const int S3 = S2 + NB * 32;
  const int S4 = S3 + NB * 128;
  for (int i = blockIdx.x * blockDim.x + threadIdx.x; i < S4;
       i += gridDim.x * blockDim.x) {
    if (i < S1) {
      z[i] = T[i];
    } else if (i < S2) {
      ld[i - S1] = 0.0f;
    } else if (i < S3) {
      int r = i - S2;
      int row = r >> 5, j = r & 31;
      A[(size_t)row * AK + j] = (f16)T[row * 64 + 32 + j];
    } else {
      int r = i - S3;
      int row = r >> 7, j = r & 127;
      A[(size_t)row * AK + 32 + j] = (f16)cond[r];
    }
  }
}

// ---------------------------------------------------------------------------
// LDS-tiled transpose: W (L x K_ x N_ f32, row-major) -> Wt (L x N_ x K_ f16).
// 64x64 tiles, coalesced reads AND writes (old version read at 4 KB stride).
// grid = (N_/64, ceil(K_/64), L), 256 threads.
// ---------------------------------------------------------------------------
__global__ void wtrans(const float* __restrict__ W, f16* __restrict__ Wt,
                       const int K_, const int N_)
{
  __shared__ float t[64][65];
  const long off = (long)blockIdx.z * K_ * N_;
  const float* Wl = W + off;
  f16* Wtl = Wt + off;
  const int k0 = blockIdx.y * 64, n0 = blockIdx.x * 64;
  const int tx = threadIdx.x & 63, ty4 = threadIdx.x >> 6;
#pragma unroll
  for (int r = ty4; r < 64; r += 4) {
    const int k = k0 + r;
    if (k < K_) t[r][tx] = Wl[(long)k * N_ + n0 + tx];
  }
  __syncthreads();
  const int k = k0 + tx;
  if (k < K_) {
#pragma unroll
    for (int r = ty4; r < 64; r += 4) {
      const int n = n0 + r;
      Wtl[(long)n * K_ + k] = (f16)t[tx][r];
    }
  }
}

// ---------------------------------------------------------------------------
// GEMM (relu): C[M x 1024] = relu(A[M x K] @ Wt^T + bias), C in f16.
// R7: 128x128 block tile, BK=32, 4 waves, wave-tile 64x64, 3 blocks/CU
// (m103 tile-space: 128^2 @ 3 blocks/CU beats 256x128 @ 2 — barrier stagger:
// while one block sits in the vmcnt(0) drain, two others compute).
// A and B both LDS double-buffered via global_load_lds; ONE barrier per
// k-step, stage(k+1) issued right after it. XOR bank swizzle (R3-validated,
// conflicts = 0): lane fetches global chunk (tid&3)^((row>>1)&3).
// ---------------------------------------------------------------------------
__global__ __launch_bounds__(256, 3)
void gemm12(const f16* __restrict__ A, const int K,   // K in {160, 1024}
            const f16* __restrict__ Wt,               // 1024 x K (pre-transposed)
            const float* __restrict__ bias,
            f16* __restrict__ C)
{
  __shared__ __align__(16) f16 As[2][128 * 32];
  __shared__ __align__(16) f16 Bs[2][128 * 32];
  const int tid  = threadIdx.x;
  const int wave = tid >> 6;
  const int lane = tid & 63;
  const int c15  = lane & 15;
  const int quad = lane >> 4;
  const int wm = (wave & 1) * 64;
  const int wn = (wave >> 1) * 64;

  // XCD swizzle: grid 2048 = 8 XCDs x 32 row-groups x 8 col-blocks, col fastest
  const int b = blockIdx.x;
  const int x = b & 7, i = b >> 3;
  const long rowStart = (long)(x * 32 + (i >> 3)) * 128;
  const long colStart = (long)(i & 7) * 128;

  const f16* Ab = A  + rowStart * K;
  const f16* Bb = Wt + colStart * K;

  // staging: lane's LDS slot fixed; fetch XOR-permuted global chunk
  const int ra  = tid >> 2;                       // 0..63 (+q*64)
  const int kca = (((tid & 3) ^ ((ra >> 1) & 3))) * 8;

  f32x4 acc[4][4] = {};
  const int nK = K >> 5;

  auto stage = [&](int kt, int sel) {
    const long ko = (long)kt * 32;
    f16* as = &As[sel][0];
    f16* bs = &Bs[sel][0];
#pragma unroll
    for (int q = 0; q < 2; ++q)
      async_copy16(Ab + (long)(q * 64 + ra) * K + ko + kca,
                   as + (q * 256 + wave * 64) * 8);
#pragma unroll
    for (int q = 0; q < 2; ++q)
      async_copy16(Bb + (long)(q * 64 + ra) * K + ko + kca,
                   bs + (q * 256 + wave * 64) * 8);
  };

  stage(0, 0);
  for (int kt = 0; kt < nK; ++kt) {
    __syncthreads();                 // drains stage(kt), issued one step ago
    if (kt + 1 < nK) stage(kt + 1, (kt + 1) & 1);
    const f16* as = &As[kt & 1][0];
    const f16* bs = &Bs[kt & 1][0];

    f16x8 a[4], bf[4];
#pragma unroll
    for (int mi = 0; mi < 4; ++mi) {
      const int R = wm + mi * 16 + c15;
      a[mi] = *(const f16x8*)&as[R * 32 + ((quad ^ ((R >> 1) & 3)) << 3)];
    }
#pragma unroll
    for (int ni = 0; ni < 4; ++ni) {
      const int R = wn + ni * 16 + c15;
      bf[ni] = *(const f16x8*)&bs[R * 32 + ((quad ^ ((R >> 1) & 3)) << 3)];
    }
#pragma unroll
    for (int mi = 0; mi < 4; ++mi)
#pragma unroll
      for (int ni = 0; ni < 4; ++ni)
        acc[mi][ni] = __builtin_amdgcn_mfma_f32_16x16x32_f16(
            a[mi], bf[ni], acc[mi][ni], 0, 0, 0);
  }

  // epilogue: bias + relu + f16 store. C/D layout: col=lane&15, row=quad*4+r
#pragma unroll
  for (int ni = 0; ni < 4; ++ni) {
    const long gn = colStart + wn + ni * 16 + c15;
    const float bv = bias[gn];
#pragma unroll
    for (int mi = 0; mi < 4; ++mi) {
#pragma unroll
      for (int r = 0; r < 4; ++r) {
        const long gm = rowStart + wm + mi * 16 + quad * 4 + r;
        float v = acc[mi][ni][r] + bv;
        v = fmaxf(v, 0.0f);
        C[gm * HID + gn] = (f16)v;
      }
    }
  }
}

// ---------------------------------------------------------------------------
// GEMM3 (N=64) + coupling epilogue. BM=128, 4 waves, wave-tile 32x64 (R3
// version, known-good). LDS-staged A and B, 1 barrier/step, XOR swizzle.
// s-col j and t-col j+32 share lane & reg slot -> no shuffles.
// Writes y to z (fp32, in d_out) and to Anext[:, :32] (f16, next layer input).
// ---------------------------------------------------------------------------
__global__ __launch_bounds__(256, 4)
void gemm3_coupling(const f16* __restrict__ X2, const f16* __restrict__ W3t,
                    const float* __restrict__ b3, float* __restrict__ z,
                    float* __restrict__ log_det, f16* __restrict__ Anext,
                    const int maskoff)
{
  __shared__ __align__(16) f16 As[2][128 * 32];
  __shared__ __align__(16) f16 Bs[2][64 * 32];
  const int tid = threadIdx.x;
  const int wave = tid >> 6, lane = tid & 63;
  const int c15 = lane & 15, quad = lane >> 4;
  const int wm = wave * 32;
  const long rowStart = (long)blockIdx.x * 128;

  const f16* Ab = X2 + rowStart * HID;
  const int ra  = tid >> 2;
  const int kca = (((tid & 3) ^ ((ra >> 1) & 3))) * 8;

  f32x4 acc[2][4] = {};

  auto stage = [&](int kt, int sel) {
    const long ko = (long)kt * 32;
    f16* as = &As[sel][0];
    f16* bs = &Bs[sel][0];
#pragma unroll
    for (int q = 0; q < 2; ++q)
      async_copy16(Ab + (long)(q * 64 + ra) * HID + ko + kca,
                   as + (q * 256 + wave * 64) * 8);
    async_copy16(W3t + (long)ra * HID + ko + kca,
                 bs + (wave * 64) * 8);
  };

  stage(0, 0);
  for (int kt = 0; kt < 32; ++kt) {
    __syncthreads();
    if (kt + 1 < 32) stage(kt + 1, (kt + 1) & 1);
    const f16* as = &As[kt & 1][0];
    const f16* bs = &Bs[kt & 1][0];

    f16x8 a[2], bf[4];
#pragma unroll
    for (int mi = 0; mi < 2; ++mi) {
      const int R = wm + mi * 16 + c15;
      a[mi] = *(const f16x8*)&as[R * 32 + ((quad ^ ((R >> 1) & 3)) << 3)];
    }
#pragma unroll
    for (int ni = 0; ni < 4; ++ni) {
      const int R = ni * 16 + c15;
      bf[ni] = *(const f16x8*)&bs[R * 32 + ((quad ^ ((R >> 1) & 3)) << 3)];
    }
#pragma unroll
    for (int mi = 0; mi < 2; ++mi)
#pragma unroll
      for (int ni = 0; ni < 4; ++ni)
        acc[mi][ni] = __builtin_amdgcn_mfma_f32_16x16x32_f16(a[mi], bf[ni], acc[mi][ni], 0, 0, 0);
  }

#pragma unroll
  for (int mi = 0; mi < 2; ++mi) {
    float sp[4] = {0.0f, 0.0f, 0.0f, 0.0f};
#pragma unroll
    for (int ni = 0; ni < 2; ++ni) {
      const int j = ni * 16 + c15;          // s-column 0..31
      const float bs = b3[j];
      const float bt = b3[32 + j];
#pragma unroll
      for (int r = 0; r < 4; ++r) {
        const long gm = rowStart + wm + mi * 16 + quad * 4 + r;
        const float sv = acc[mi][ni][r] + bs;
        const float e2 = __expf(2.0f * sv);            // tanh via exp
        const float s  = 1.0f - 2.0f / (e2 + 1.0f);
        const float tv = acc[mi][ni + 2][r] + bt;
        const float m  = z[gm * 64 + maskoff + j];
        const float y  = fmaf(m, __expf(s), tv);
        z[gm * 64 + maskoff + j] = y;
        Anext[gm * AK + j] = (f16)y;   // next layer's unmasked input
        sp[r] += s;
      }
    }
#pragma unroll
    for (int r = 0; r < 4; ++r) {
      float v = sp[r];
      v += __shfl_xor(v, 1);
      v += __shfl_xor(v, 2);
      v += __shfl_xor(v, 4);
      v += __shfl_xor(v, 8);
      if (c15 == 0) {
        const long gm = rowStart + wm + mi * 16 + quad * 4 + r;
        log_det[gm] += v;   // only this thread touches this row this layer
      }
    }
  }
}

// ---------------------------------------------------------------------------
extern "C" void kernel_launch(void* const* d_in, const int* in_sizes, int n_in,
                              void* d_out, int out_size, void* d_ws, size_t ws_size,
                              hipStream_t stream) {
  (void)in_sizes; (void)n_in; (void)out_size; (void)ws_size;
  const float* T    = (const float*)d_in[0];
  const float* cond = (const float*)d_in[1];
  const float* W1   = (const float*)d_in[2];
  const float* b1   = (const float*)d_in[3];
  const float* W2   = (const float*)d_in[4];
  const float* b2   = (const float*)d_in[5];
  const float* W3   = (const float*)d_in[6];
  const float* b3   = (const float*)d_in[7];

  float* z  = (float*)d_out;                 // B x 64 working state = output
  float* ld = z + (size_t)NB * 64;           // B log_det

  f16* A   = (f16*)d_ws;                     // B x 160
  f16* X1  = A   + (size_t)NB * AK;          // B x 1024
  f16* X2  = X1  + (size_t)NB * HID;         // B x 1024
  f16* W1t = X2  + (size_t)NB * HID;         // 6 x 1024 x 160
  f16* W2t = W1t + (size_t)6 * 1024 * 160;   // 6 x 1024 x 1024
  f16* W3t = W2t + ((size_t)6 << 20);        // 6 x 64 x 1024

  prep_batch<<<2048, 256, 0, stream>>>(T, cond, z, ld, A);
  wtrans<<<dim3(16, 3, 6),  256, 0, stream>>>(W1, W1t, AK, 1024);
  wtrans<<<dim3(16, 16, 6), 256, 0, stream>>>(W2, W2t, HID, 1024);
  wtrans<<<dim3(1, 16, 6),  256, 0, stream>>>(W3, W3t, HID, 64);

  const int g12 = (NB / 128) * (HID / 128);  // 2048 blocks
  for (int l = 0; l < LAYERS; ++l) {
    gemm12<<<g12, 256, 0, stream>>>(A, AK, W1t + (size_t)l * 1024 * AK,
                                    b1 + l * 1024, X1);
    gemm12<<<g12, 256, 0, stream>>>(X1, HID, W2t + ((size_t)l << 20),
                                    b2 + l * 1024, X2);
    const int maskoff = (l & 1) ? 32 : 0;
    gemm3_coupling<<<NB / 128, 256, 0, stream>>>(X2, W3t + (size_t)l * 64 * 1024,
                                                 b3 + l * 64, z, ld, A, maskoff);
  }
}

// Round 8
// 870.403 us; speedup vs baseline: 1.4893x; 1.0337x over previous
//
#include <hip/hip_runtime.h>
#include <hip/hip_fp16.h>
#include <stdint.h>

typedef _Float16 f16;
typedef _Float16 f16x8 __attribute__((ext_vector_type(8)));
typedef float f32x4 __attribute__((ext_vector_type(4)));

#define NB 32768      // batch
#define LAYERS 6
#define AK 160        // HALF + COND
#define HID 1024

// async global->LDS, 16B per lane. LDS dest is wave-uniform base + lane*16.
__device__ __forceinline__ void async_copy16(const void* g, void* l) {
  __builtin_amdgcn_global_load_lds(
      (const __attribute__((address_space(1))) void*)g,
      (__attribute__((address_space(3))) void*)l, 16, 0, 0);
}

// ---------------------------------------------------------------------------
// prep: z = T (fp32 working state lives in d_out), log_det = 0,
// A[:, :32] = f16(T[:, 32:]) (layer0 unmasked), A[:, 32:160] = f16(cond)
// ---------------------------------------------------------------------------
__global__ void prep_batch(const float* __restrict__ T, const float* __restrict__ cond,
                           float* __restrict__ z, float* __restrict__ ld,
                           f16* __restrict__ A)
{
  const int S1 = NB * 64;
  const int S2 = S1 + NB;
  const int S3 = S2 + NB * 32;
  const int S4 = S3 + NB * 128;
  for (int i = blockIdx.x * blockDim.x + threadIdx.x; i < S4;
       i += gridDim.x * blockDim.x) {
    if (i < S1) {
      z[i] = T[i];
    } else if (i < S2) {
      ld[i - S1] = 0.0f;
    } else if (i < S3) {
      int r = i - S2;
      int row = r >> 5, j = r & 31;
      A[(size_t)row * AK + j] = (f16)T[row * 64 + 32 + j];
    } else {
      int r = i - S3;
      int row = r >> 7, j = r & 127;
      A[(size_t)row * AK + 32 + j] = (f16)cond[r];
    }
  }
}

// ---------------------------------------------------------------------------
// LDS-tiled transpose: W (L x K_ x N_ f32, row-major) -> Wt (L x N_ x K_ f16).
// 64x64 tiles, coalesced reads AND writes.
// grid = (N_/64, ceil(K_/64), L), 256 threads.
// ---------------------------------------------------------------------------
__global__ void wtrans(const float* __restrict__ W, f16* __restrict__ Wt,
                       const int K_, const int N_)
{
  __shared__ float t[64][65];
  const long off = (long)blockIdx.z * K_ * N_;
  const float* Wl = W + off;
  f16* Wtl = Wt + off;
  const int k0 = blockIdx.y * 64, n0 = blockIdx.x * 64;
  const int tx = threadIdx.x & 63, ty4 = threadIdx.x >> 6;
#pragma unroll
  for (int r = ty4; r < 64; r += 4) {
    const int k = k0 + r;
    if (k < K_) t[r][tx] = Wl[(long)k * N_ + n0 + tx];
  }
  __syncthreads();
  const int k = k0 + tx;
  if (k < K_) {
#pragma unroll
    for (int r = ty4; r < 64; r += 4) {
      const int n = n0 + r;
      Wtl[(long)n * K_ + k] = (f16)t[tx][r];
    }
  }
}

// ---------------------------------------------------------------------------
// GEMM1 (K=160): C[M x 1024] = relu(A[M x 160] @ W1t^T + b1), C in f16.
// K is tiny -> the ENTIRE 128x160 A-tile and B-tile fit in LDS (80 KB,
// 2 blocks/CU). Stage everything (20 issues), ONE barrier, then 80 MFMA
// straight with zero k-loop barriers. Same XOR bank swizzle (row stride
// 320 B = 16 banks mod 32 -> identical 2-way-free pattern as gemm12).
// ---------------------------------------------------------------------------
__global__ __launch_bounds__(256, 2)
void gemm1_full(const f16* __restrict__ A,
                const f16* __restrict__ Wt,       // 1024 x 160
                const float* __restrict__ bias,
                f16* __restrict__ C)
{
  __shared__ __align__(16) f16 As[128 * 160];     // 40 KB
  __shared__ __align__(16) f16 Bs[128 * 160];     // 40 KB
  const int tid  = threadIdx.x;
  const int lane = tid & 63;
  const int wave = tid >> 6;
  const int c15  = lane & 15;
  const int quad = lane >> 4;
  const int wm = (wave & 1) * 64;
  const int wn = (wave >> 1) * 64;

  const int b = blockIdx.x;
  const int x = b & 7, i = b >> 3;
  const long rowStart = (long)(x * 32 + (i >> 3)) * 128;
  const long colStart = (long)(i & 7) * 128;

  const f16* Ab = A  + rowStart * AK;
  const f16* Bb = Wt + colStart * AK;

  // stage both tiles fully: 2560 chunks each = 10 issues of 256.
  // slot f holds global chunk (f%20)^((row>>1)&3) of row f/20.
#pragma unroll
  for (int it = 0; it < 10; ++it) {
    const int f = it * 256 + tid;
    const int row = f / 20;
    const int ch  = f - row * 20;
    const int chs = ch ^ ((row >> 1) & 3);
    async_copy16(Ab + (long)row * AK + chs * 8, &As[0] + (long)f * 8);
    async_copy16(Bb + (long)row * AK + chs * 8, &Bs[0] + (long)f * 8);
  }
  __syncthreads();   // single barrier; compiler drains vmcnt(0) here

  f32x4 acc[4][4] = {};
#pragma unroll
  for (int kt = 0; kt < 5; ++kt) {
    f16x8 a[4], bf[4];
#pragma unroll
    for (int mi = 0; mi < 4; ++mi) {
      const int R = wm + mi * 16 + c15;
      a[mi] = *(const f16x8*)&As[(R * 20 + kt * 4 + (quad ^ ((R >> 1) & 3))) * 8];
    }
#pragma unroll
    for (int ni = 0; ni < 4; ++ni) {
      const int R = wn + ni * 16 + c15;
      bf[ni] = *(const f16x8*)&Bs[(R * 20 + kt * 4 + (quad ^ ((R >> 1) & 3))) * 8];
    }
#pragma unroll
    for (int mi = 0; mi < 4; ++mi)
#pragma unroll
      for (int ni = 0; ni < 4; ++ni)
        acc[mi][ni] = __builtin_amdgcn_mfma_f32_16x16x32_f16(
            a[mi], bf[ni], acc[mi][ni], 0, 0, 0);
  }

#pragma unroll
  for (int ni = 0; ni < 4; ++ni) {
    const long gn = colStart + wn + ni * 16 + c15;
    const float bv = bias[gn];
#pragma unroll
    for (int mi = 0; mi < 4; ++mi) {
#pragma unroll
      for (int r = 0; r < 4; ++r) {
        const long gm = rowStart + wm + mi * 16 + quad * 4 + r;
        float v = acc[mi][ni][r] + bv;
        v = fmaxf(v, 0.0f);
        C[gm * HID + gn] = (f16)v;
      }
    }
  }
}

// ---------------------------------------------------------------------------
// GEMM2 (K=1024): R7 structure, unchanged (measured plateau ~88 us).
// 128x128 block tile, BK=32, 4 waves, wave-tile 64x64, 3 blocks/CU.
// A,B LDS double-buffered; ONE barrier per k-step; XOR swizzle (0 conflicts).
// ---------------------------------------------------------------------------
__global__ __launch_bounds__(256, 3)
void gemm12(const f16* __restrict__ A, const int K,
            const f16* __restrict__ Wt,
            const float* __restrict__ bias,
            f16* __restrict__ C)
{
  __shared__ __align__(16) f16 As[2][128 * 32];
  __shared__ __align__(16) f16 Bs[2][128 * 32];
  const int tid  = threadIdx.x;
  const int wave = tid >> 6;
  const int lane = tid & 63;
  const int c15  = lane & 15;
  const int quad = lane >> 4;
  const int wm = (wave & 1) * 64;
  const int wn = (wave >> 1) * 64;

  const int b = blockIdx.x;
  const int x = b & 7, i = b >> 3;
  const long rowStart = (long)(x * 32 + (i >> 3)) * 128;
  const long colStart = (long)(i & 7) * 128;

  const f16* Ab = A  + rowStart * K;
  const f16* Bb = Wt + colStart * K;

  const int ra  = tid >> 2;
  const int kca = (((tid & 3) ^ ((ra >> 1) & 3))) * 8;

  f32x4 acc[4][4] = {};
  const int nK = K >> 5;

  auto stage = [&](int kt, int sel) {
    const long ko = (long)kt * 32;
    f16* as = &As[sel][0];
    f16* bs = &Bs[sel][0];
#pragma unroll
    for (int q = 0; q < 2; ++q)
      async_copy16(Ab + (long)(q * 64 + ra) * K + ko + kca,
                   as + (q * 256 + wave * 64) * 8);
#pragma unroll
    for (int q = 0; q < 2; ++q)
      async_copy16(Bb + (long)(q * 64 + ra) * K + ko + kca,
                   bs + (q * 256 + wave * 64) * 8);
  };

  stage(0, 0);
  for (int kt = 0; kt < nK; ++kt) {
    __syncthreads();
    if (kt + 1 < nK) stage(kt + 1, (kt + 1) & 1);
    const f16* as = &As[kt & 1][0];
    const f16* bs = &Bs[kt & 1][0];

    f16x8 a[4], bf[4];
#pragma unroll
    for (int mi = 0; mi < 4; ++mi) {
      const int R = wm + mi * 16 + c15;
      a[mi] = *(const f16x8*)&as[R * 32 + ((quad ^ ((R >> 1) & 3)) << 3)];
    }
#pragma unroll
    for (int ni = 0; ni < 4; ++ni) {
      const int R = wn + ni * 16 + c15;
      bf[ni] = *(const f16x8*)&bs[R * 32 + ((quad ^ ((R >> 1) & 3)) << 3)];
    }
#pragma unroll
    for (int mi = 0; mi < 4; ++mi)
#pragma unroll
      for (int ni = 0; ni < 4; ++ni)
        acc[mi][ni] = __builtin_amdgcn_mfma_f32_16x16x32_f16(
            a[mi], bf[ni], acc[mi][ni], 0, 0, 0);
  }

#pragma unroll
  for (int ni = 0; ni < 4; ++ni) {
    const long gn = colStart + wn + ni * 16 + c15;
    const float bv = bias[gn];
#pragma unroll
    for (int mi = 0; mi < 4; ++mi) {
#pragma unroll
      for (int r = 0; r < 4; ++r) {
        const long gm = rowStart + wm + mi * 16 + quad * 4 + r;
        float v = acc[mi][ni][r] + bv;
        v = fmaxf(v, 0.0f);
        C[gm * HID + gn] = (f16)v;
      }
    }
  }
}

// ---------------------------------------------------------------------------
// GEMM3 (N=64) + coupling epilogue. R8: BM=64, grid 512 -> 2 blocks/CU
// (R7's BM=128/grid-256 ran 1 block/CU: no barrier stagger, latency-exposed).
// 4 waves x wave-tile 16x64. LDS dbuf 2 x 8 KB, 1 barrier/step, XOR swizzle.
// s-col j and t-col j+32 share lane & reg slot -> no shuffles.
// Writes y to z (fp32, in d_out) and to Anext[:, :32] (f16, next layer input).
// ---------------------------------------------------------------------------
__global__ __launch_bounds__(256, 4)
void gemm3_coupling(const f16* __restrict__ X2, const f16* __restrict__ W3t,
                    const float* __restrict__ b3, float* __restrict__ z,
                    float* __restrict__ log_det, f16* __restrict__ Anext,
                    const int maskoff)
{
  __shared__ __align__(16) f16 As[2][64 * 32];
  __shared__ __align__(16) f16 Bs[2][64 * 32];
  const int tid = threadIdx.x;
  const int wave = tid >> 6, lane = tid & 63;
  const int c15 = lane & 15, quad = lane >> 4;
  const int wm = wave * 16;
  const long rowStart = (long)blockIdx.x * 64;

  const f16* Ab = X2 + rowStart * HID;
  const int ra  = tid >> 2;                        // 0..63
  const int kca = (((tid & 3) ^ ((ra >> 1) & 3))) * 8;

  f32x4 acc[4] = {};

  auto stage = [&](int kt, int sel) {
    const long ko = (long)kt * 32;
    async_copy16(Ab + (long)ra * HID + ko + kca,
                 &As[sel][0] + (wave * 64) * 8);
    async_copy16(W3t + (long)ra * HID + ko + kca,
                 &Bs[sel][0] + (wave * 64) * 8);
  };

  stage(0, 0);
  for (int kt = 0; kt < 32; ++kt) {
    __syncthreads();
    if (kt + 1 < 32) stage(kt + 1, (kt + 1) & 1);
    const f16* as = &As[kt & 1][0];
    const f16* bs = &Bs[kt & 1][0];

    const int Ra = wm + c15;
    f16x8 a = *(const f16x8*)&as[Ra * 32 + ((quad ^ ((Ra >> 1) & 3)) << 3)];
    f16x8 bf[4];
#pragma unroll
    for (int ni = 0; ni < 4; ++ni) {
      const int R = ni * 16 + c15;
      bf[ni] = *(const f16x8*)&bs[R * 32 + ((quad ^ ((R >> 1) & 3)) << 3)];
    }
#pragma unroll
    for (int ni = 0; ni < 4; ++ni)
      acc[ni] = __builtin_amdgcn_mfma_f32_16x16x32_f16(a, bf[ni], acc[ni], 0, 0, 0);
  }

  float sp[4] = {0.0f, 0.0f, 0.0f, 0.0f};
#pragma unroll
  for (int ni = 0; ni < 2; ++ni) {
    const int j = ni * 16 + c15;          // s-column 0..31
    const float bs = b3[j];
    const float bt = b3[32 + j];
#pragma unroll
    for (int r = 0; r < 4; ++r) {
      const long gm = rowStart + wm + quad * 4 + r;
      const float sv = acc[ni][r] + bs;
      const float e2 = __expf(2.0f * sv);            // tanh via exp
      const float s  = 1.0f - 2.0f / (e2 + 1.0f);
      const float tv = acc[ni + 2][r] + bt;
      const float m  = z[gm * 64 + maskoff + j];
      const float y  = fmaf(m, __expf(s), tv);
      z[gm * 64 + maskoff + j] = y;
      Anext[gm * AK + j] = (f16)y;   // next layer's unmasked input
      sp[r] += s;
    }
  }
#pragma unroll
  for (int r = 0; r < 4; ++r) {
    float v = sp[r];
    v += __shfl_xor(v, 1);
    v += __shfl_xor(v, 2);
    v += __shfl_xor(v, 4);
    v += __shfl_xor(v, 8);
    if (c15 == 0) {
      const long gm = rowStart + wm + quad * 4 + r;
      log_det[gm] += v;   // only this thread touches this row this layer
    }
  }
}

// ---------------------------------------------------------------------------
extern "C" void kernel_launch(void* const* d_in, const int* in_sizes, int n_in,
                              void* d_out, int out_size, void* d_ws, size_t ws_size,
                              hipStream_t stream) {
  (void)in_sizes; (void)n_in; (void)out_size; (void)ws_size;
  const float* T    = (const float*)d_in[0];
  const float* cond = (const float*)d_in[1];
  const float* W1   = (const float*)d_in[2];
  const float* b1   = (const float*)d_in[3];
  const float* W2   = (const float*)d_in[4];
  const float* b2   = (const float*)d_in[5];
  const float* W3   = (const float*)d_in[6];
  const float* b3   = (const float*)d_in[7];

  float* z  = (float*)d_out;                 // B x 64 working state = output
  float* ld = z + (size_t)NB * 64;           // B log_det

  f16* A   = (f16*)d_ws;                     // B x 160
  f16* X1  = A   + (size_t)NB * AK;          // B x 1024
  f16* X2  = X1  + (size_t)NB * HID;         // B x 1024
  f16* W1t = X2  + (size_t)NB * HID;         // 6 x 1024 x 160
  f16* W2t = W1t + (size_t)6 * 1024 * 160;   // 6 x 1024 x 1024
  f16* W3t = W2t + ((size_t)6 << 20);        // 6 x 64 x 1024

  prep_batch<<<2048, 256, 0, stream>>>(T, cond, z, ld, A);
  wtrans<<<dim3(16, 3, 6),  256, 0, stream>>>(W1, W1t, AK, 1024);
  wtrans<<<dim3(16, 16, 6), 256, 0, stream>>>(W2, W2t, HID, 1024);
  wtrans<<<dim3(1, 16, 6),  256, 0, stream>>>(W3, W3t, HID, 64);

  const int g12 = (NB / 128) * (HID / 128);  // 2048 blocks
  for (int l = 0; l < LAYERS; ++l) {
    gemm1_full<<<g12, 256, 0, stream>>>(A, W1t + (size_t)l * 1024 * AK,
                                        b1 + l * 1024, X1);
    gemm12<<<g12, 256, 0, stream>>>(X1, HID, W2t + ((size_t)l << 20),
                                    b2 + l * 1024, X2);
    const int maskoff = (l & 1) ? 32 : 0;
    gemm3_coupling<<<NB / 64, 256, 0, stream>>>(X2, W3t + (size_t)l * 64 * 1024,
                                                b3 + l * 64, z, ld, A, maskoff);
  }
}